// Round 24
// baseline (359.359 us; speedup 1.0000x reference)
//
#include <hip/hip_runtime.h>

typedef __attribute__((ext_vector_type(8))) short bf16x8;
typedef __attribute__((ext_vector_type(4))) float f32x4;
typedef __attribute__((ext_vector_type(4))) int i32x4;
typedef unsigned short u16;
typedef unsigned int u32;

#define B_ 8
#define T_ 512
#define C_ 1024
#define I_ 4096
#define H_ 16
#define Dh_ 64
#define BT (B_*T_)
#define NH (B_*H_)

// ---------------- helpers ----------------
__device__ __forceinline__ float bf2f(u16 u) {
  return __uint_as_float(((u32)u) << 16);
}
__device__ __forceinline__ u16 f2bf(float f) {
  u32 u = __float_as_uint(f);
  u32 r = u + 0x7FFFu + ((u >> 16) & 1u);
  return (u16)(r >> 16);
}
__device__ __forceinline__ float wredMax(float v) {
#pragma unroll
  for (int o = 32; o; o >>= 1) v = fmaxf(v, __shfl_xor(v, o));
  return v;
}
__device__ __forceinline__ float wredSum(float v) {
#pragma unroll
  for (int o = 32; o; o >>= 1) v += __shfl_xor(v, o);
  return v;
}
// 64-slot strided max array (one 64B line per slot).
__device__ __forceinline__ void slotAtomicMax(u32* arr, int bid, float bm) {
  u32 b = __float_as_uint(bm);
  volatile u32* p = arr + ((bid & 63) << 4);
  if (b > *p) atomicMax((u32*)p, b);
}
__device__ __forceinline__ float slotMax(const u32* __restrict__ arr) {
  float m = 0.f;
#pragma unroll
  for (int i = 0; i < 64; ++i) m = fmaxf(m, __uint_as_float(arr[i << 4]));
  return m;
}
// device-coherent slot read (after grid barrier)
__device__ __forceinline__ float slotMaxAcq(const u32* __restrict__ arr) {
  float m = 0.f;
#pragma unroll
  for (int i = 0; i < 64; ++i) {
    u32 v = __hip_atomic_load(arr + (i << 4), __ATOMIC_RELAXED, __HIP_MEMORY_SCOPE_AGENT);
    m = fmaxf(m, __uint_as_float(v));
  }
  return m;
}
// spin grid-barrier (all blocks co-resident: grid <= 256, 1 block/CU by LDS).
// tid==0 only; caller wraps with __syncthreads().
__device__ __forceinline__ void gridBarrier(u32* ctr, u32 n) {
  __hip_atomic_fetch_add(ctr, 1u, __ATOMIC_ACQ_REL, __HIP_MEMORY_SCOPE_AGENT);
  u32 v;
  do {
    v = __hip_atomic_load(ctr, __ATOMIC_ACQUIRE, __HIP_MEMORY_SCOPE_AGENT);
    if (v < n) __builtin_amdgcn_s_sleep(8);
  } while (v < n);
}
__device__ __forceinline__ void gload16(const void* g, void* l) {
  __builtin_amdgcn_global_load_lds((const __attribute__((address_space(1))) void*)g,
                                   (__attribute__((address_space(3))) void*)l, 16, 0, 0);
}
__device__ __forceinline__ int qi(float v, float inv) {
  return (int)fminf(fmaxf(rintf(v * inv), -127.f), 127.f);
}
__device__ __forceinline__ float gelu1(float v) {
  float x2 = v * v;
  float e = __expf(v * fmaf(-0.0713548755f, x2, -1.5957691216f));
  return v * __builtin_amdgcn_rcpf(1.0f + e);
}

// ---------------- small kernels ----------------
// zero slot arrays (8 x 1024 u32) + grid-barrier counters
__global__ void k_init(u32* s) {
  int i = blockIdx.x * 256 + threadIdx.x;
  if (i < 8704) s[i] = 0u;
}

// fused: blocks [0,512) = absmax of 4 weight arrays -> slots 0..3
//        blocks [512, 512+BT) = LayerNorm1 (f32 in, bf16 out) -> slot arr
__global__ __launch_bounds__(256) void k_pre1(
    const float* __restrict__ p0, int n0,
    const float* __restrict__ p1, int n1,
    const float* __restrict__ p2, int n2,
    const float* __restrict__ p3, int n3,
    u32* __restrict__ scw,
    const float* __restrict__ x, const float* __restrict__ g,
    const float* __restrict__ b, u16* __restrict__ y,
    u32* __restrict__ arr) {
  const int t = threadIdx.x;
  if (blockIdx.x < 512) {
    int stride = 512 * 256;
    int gid = blockIdx.x * 256 + t;
    float m0 = 0.f, m1 = 0.f, m2 = 0.f, m3 = 0.f;
    for (int i = gid; i < n0; i += stride) {
      float4 v = ((const float4*)p0)[i];
      m0 = fmaxf(m0, fmaxf(fmaxf(fabsf(v.x), fabsf(v.y)), fmaxf(fabsf(v.z), fabsf(v.w))));
    }
    for (int i = gid; i < n1; i += stride) {
      float4 v = ((const float4*)p1)[i];
      m1 = fmaxf(m1, fmaxf(fmaxf(fabsf(v.x), fabsf(v.y)), fmaxf(fabsf(v.z), fabsf(v.w))));
    }
    for (int i = gid; i < n2; i += stride) {
      float4 v = ((const float4*)p2)[i];
      m2 = fmaxf(m2, fmaxf(fmaxf(fabsf(v.x), fabsf(v.y)), fmaxf(fabsf(v.z), fabsf(v.w))));
    }
    for (int i = gid; i < n3; i += stride) {
      float4 v = ((const float4*)p3)[i];
      m3 = fmaxf(m3, fmaxf(fmaxf(fabsf(v.x), fabsf(v.y)), fmaxf(fabsf(v.z), fabsf(v.w))));
    }
    m0 = wredMax(m0); m1 = wredMax(m1); m2 = wredMax(m2); m3 = wredMax(m3);
    __shared__ float red4[4][4];
    int wid = t >> 6, lane = t & 63;
    if (lane == 0) { red4[wid][0] = m0; red4[wid][1] = m1; red4[wid][2] = m2; red4[wid][3] = m3; }
    __syncthreads();
    if (t < 4) {
      int j = t;
      float bm = fmaxf(fmaxf(red4[0][j], red4[1][j]), fmaxf(red4[2][j], red4[3][j]));
      slotAtomicMax(scw + j * 1024, blockIdx.x, bm);
    }
  } else {
    int row = blockIdx.x - 512;
    float4 v = ((const float4*)(x + (long)row * C_))[t];
    float s1 = v.x + v.y + v.z + v.w;
    float s2 = v.x * v.x + v.y * v.y + v.z * v.z + v.w * v.w;
    s1 = wredSum(s1);
    s2 = wredSum(s2);
    __shared__ float red[8];
    int wid = t >> 6, lane = t & 63;
    if (lane == 0) { red[wid] = s1; red[4 + wid] = s2; }
    __syncthreads();
    s1 = red[0] + red[1] + red[2] + red[3];
    s2 = red[4] + red[5] + red[6] + red[7];
    float mean = s1 * (1.0f / C_);
    float var = s2 * (1.0f / C_) - mean * mean;
    float inv = rsqrtf(var + 1e-5f);
    float4 gv = ((const float4*)g)[t];
    float4 bv = ((const float4*)b)[t];
    float4 o;
    o.x = (v.x - mean) * inv * gv.x + bv.x;
    o.y = (v.y - mean) * inv * gv.y + bv.y;
    o.z = (v.z - mean) * inv * gv.z + bv.z;
    o.w = (v.w - mean) * inv * gv.w + bv.w;
    ushort4 ob;
    ob.x = f2bf(o.x); ob.y = f2bf(o.y); ob.z = f2bf(o.z); ob.w = f2bf(o.w);
    ((ushort4*)(y + (long)row * C_))[t] = ob;
    float m = fmaxf(fmaxf(fabsf(o.x), fabsf(o.y)), fmaxf(fabsf(o.z), fabsf(o.w)));
    m = wredMax(m);
    __syncthreads();
    if (lane == 0) red[wid] = m;
    __syncthreads();
    if (t == 0) {
      float bm = fmaxf(fmaxf(red[0], red[1]), fmaxf(red[2], red[3]));
      slotAtomicMax(arr, row, bm);
    }
  }
}

// fused: blocks [0,512) = quantize 4 weight arrays -> i8 (scales slots 0..3)
//        blocks [512,1024) = quantize x1 bf16 -> i8 (scale arrX)
__global__ __launch_bounds__(256) void k_pre2(
    const float* __restrict__ p0, signed char* __restrict__ q0, int n0,
    const float* __restrict__ p1, signed char* __restrict__ q1, int n1,
    const float* __restrict__ p2, signed char* __restrict__ q2, int n2,
    const float* __restrict__ p3, signed char* __restrict__ q3, int n3,
    const u32* __restrict__ scw,
    const u16* __restrict__ xb, signed char* __restrict__ xq, int n8,
    const u32* __restrict__ arrX) {
  const int t = threadIdx.x;
  if (blockIdx.x < 512) {
    int stride = 512 * 256;
    int gid = blockIdx.x * 256 + t;
#define QLOOP(p, q, n, slot)                                                        \
    {                                                                               \
      float s = fmaxf(slotMax(scw + slot * 1024) * (1.0f / 127.0f), 1e-8f);         \
      float inv = 1.0f / s;                                                         \
      for (int i = gid; i < n; i += stride) {                                       \
        float4 v = ((const float4*)p)[i];                                           \
        u32 pk = (u32)(qi(v.x, inv) & 255) | ((u32)(qi(v.y, inv) & 255) << 8) |     \
                 ((u32)(qi(v.z, inv) & 255) << 16) | ((u32)(qi(v.w, inv) & 255) << 24); \
        ((u32*)q)[i] = pk;                                                          \
      }                                                                             \
    }
    QLOOP(p0, q0, n0, 0)
    QLOOP(p1, q1, n1, 1)
    QLOOP(p2, q2, n2, 2)
    QLOOP(p3, q3, n3, 3)
#undef QLOOP
  } else {
    float s = fmaxf(slotMax(arrX) * (1.0f / 127.0f), 1e-8f);
    float inv = 1.0f / s;
    int stride = 512 * 256;
    for (int i = (blockIdx.x - 512) * 256 + t; i < n8; i += stride) {
      uint4 d = ((const uint4*)xb)[i];
      u16* e = (u16*)&d;
      uint2 o;
      o.x = (u32)(qi(bf2f(e[0]), inv) & 255) | ((u32)(qi(bf2f(e[1]), inv) & 255) << 8) |
            ((u32)(qi(bf2f(e[2]), inv) & 255) << 16) | ((u32)(qi(bf2f(e[3]), inv) & 255) << 24);
      o.y = (u32)(qi(bf2f(e[4]), inv) & 255) | ((u32)(qi(bf2f(e[5]), inv) & 255) << 8) |
            ((u32)(qi(bf2f(e[6]), inv) & 255) << 16) | ((u32)(qi(bf2f(e[7]), inv) & 255) << 24);
      ((uint2*)xq)[i] = o;
    }
  }
}

__global__ __launch_bounds__(256) void k_quant_b8(const u16* __restrict__ x, signed char* __restrict__ q,
                                                  int n8, const u32* __restrict__ arr) {
  float s = fmaxf(slotMax(arr) * (1.0f / 127.0f), 1e-8f);
  float inv = 1.0f / s;
  int stride = gridDim.x * blockDim.x;
  for (int i = blockIdx.x * blockDim.x + threadIdx.x; i < n8; i += stride) {
    uint4 d = ((const uint4*)x)[i];
    u16* e = (u16*)&d;
    uint2 o;
    o.x = (u32)(qi(bf2f(e[0]), inv) & 255) | ((u32)(qi(bf2f(e[1]), inv) & 255) << 8) |
          ((u32)(qi(bf2f(e[2]), inv) & 255) << 16) | ((u32)(qi(bf2f(e[3]), inv) & 255) << 24);
    o.y = (u32)(qi(bf2f(e[4]), inv) & 255) | ((u32)(qi(bf2f(e[5]), inv) & 255) << 8) |
          ((u32)(qi(bf2f(e[6]), inv) & 255) << 16) | ((u32)(qi(bf2f(e[7]), inv) & 255) << 24);
    ((uint2*)q)[i] = o;
  }
}

// LayerNorm over bf16 input rows (C=1024) -> bf16 out + slot absmax (LN2)
__global__ __launch_bounds__(256) void k_lnb(const u16* __restrict__ x, const float* __restrict__ g,
                                             const float* __restrict__ b, u16* __restrict__ y,
                                             u32* __restrict__ arr) {
  int row = blockIdx.x;
  int t = threadIdx.x;
  ushort4 xb = ((const ushort4*)(x + (long)row * C_))[t];
  float4 v;
  v.x = bf2f(xb.x); v.y = bf2f(xb.y); v.z = bf2f(xb.z); v.w = bf2f(xb.w);
  float s1 = v.x + v.y + v.z + v.w;
  float s2 = v.x * v.x + v.y * v.y + v.z * v.z + v.w * v.w;
  s1 = wredSum(s1);
  s2 = wredSum(s2);
  __shared__ float red[8];
  int wid = t >> 6, lane = t & 63;
  if (lane == 0) { red[wid] = s1; red[4 + wid] = s2; }
  __syncthreads();
  s1 = red[0] + red[1] + red[2] + red[3];
  s2 = red[4] + red[5] + red[6] + red[7];
  float mean = s1 * (1.0f / C_);
  float var = s2 * (1.0f / C_) - mean * mean;
  float inv = rsqrtf(var + 1e-5f);
  float4 gv = ((const float4*)g)[t];
  float4 bv = ((const float4*)b)[t];
  float4 o;
  o.x = (v.x - mean) * inv * gv.x + bv.x;
  o.y = (v.y - mean) * inv * gv.y + bv.y;
  o.z = (v.z - mean) * inv * gv.z + bv.z;
  o.w = (v.w - mean) * inv * gv.w + bv.w;
  ushort4 ob;
  ob.x = f2bf(o.x); ob.y = f2bf(o.y); ob.z = f2bf(o.z); ob.w = f2bf(o.w);
  ((ushort4*)(y + (long)row * C_))[t] = ob;
  float m = fmaxf(fmaxf(fabsf(o.x), fabsf(o.y)), fmaxf(fabsf(o.z), fabsf(o.w)));
  m = wredMax(m);
  __syncthreads();
  if (lane == 0) red[wid] = m;
  __syncthreads();
  if (t == 0) {
    float bm = fmaxf(fmaxf(red[0], red[1]), fmaxf(red[2], red[3]));
    slotAtomicMax(arr, row, bm);
  }
}

// ---------------- fused attention + in-kernel O quant ----------------
// grid = 256 blocks, 1 block/CU (150KB LDS) -> co-resident; spin grid-barrier
// then each block quantizes its OWN O tile (same-XCD L2 hot).
__global__ __launch_bounds__(256, 1) void k_attn(
    const u16* __restrict__ qkv, const float* __restrict__ mask,
    u16* __restrict__ O, u32* __restrict__ amax,
    signed char* __restrict__ Oq, u32* __restrict__ ctr) {
  __shared__ u16 Ke[512 * 64];
  __shared__ u16 Vt[64 * 512];
  __shared__ u16 Pl[4 * 64 * 40];
  __shared__ float extl[512];
  __shared__ float redm[4];
  const int tid = threadIdx.x;
  const int w = tid >> 6, l = tid & 63;
  const int head = blockIdx.x;
  const int chunk = blockIdx.y;
  const int b = head >> 4, h = head & 15;
  const long rowbase = (long)(b * 512) * (3 * C_);

  {
    const u16* Kg = qkv + rowbase + C_ + h * 64;
    int lr8 = l >> 3;
    int ls = (l & 7) ^ lr8;
    const long koff = (long)lr8 * (3 * C_) + ls * 8;
#pragma unroll
    for (int i = 0; i < 16; ++i) {
      int r0 = w * 128 + i * 8;
      gload16(Kg + (long)r0 * (3 * C_) + koff, &Ke[r0 * 64]);
    }
  }
  {
    const u16* Vg = qkv + rowbase + 2 * C_ + h * 64;
    int kvl = tid & 31;
    int d0 = (tid >> 5) * 8;
#pragma unroll 4
    for (int i = 0; i < 16; ++i) {
      int kv = i * 32 + kvl;
      uint4 t4 = *(const uint4*)(Vg + (long)kv * (3 * C_) + d0);
      u16* tv = (u16*)&t4;
      int slot = kv >> 3, within = kv & 7;
#pragma unroll
      for (int j = 0; j < 8; ++j) {
        int d = d0 + j;
        Vt[d * 512 + ((slot ^ (d & 7)) << 3) + within] = tv[j];
      }
    }
  }
  {
    const float* mb = mask + b * 512;
    extl[tid] = (1.0f - mb[tid]) * -10000.0f;
    extl[tid + 256] = (1.0f - mb[tid + 256]) * -10000.0f;
  }
  const int qbase = chunk * 256 + w * 64;
  bf16x8 qf[4][2];
  {
    const u16* Qg = qkv + rowbase + h * 64;
#pragma unroll
    for (int qt = 0; qt < 4; ++qt)
#pragma unroll
      for (int dc = 0; dc < 2; ++dc)
        qf[qt][dc] = *(const bf16x8*)(Qg + (long)(qbase + qt * 16 + (l & 15)) * (3 * C_) + dc * 32 + (l >> 4) * 8);
  }
  __syncthreads();

  f32x4 oacc[4][4];
  float mrun[4], lrun[4];
#pragma unroll
  for (int qt = 0; qt < 4; ++qt) { mrun[qt] = -3.0e38f; lrun[qt] = 0.f; }
#pragma unroll
  for (int dt = 0; dt < 4; ++dt)
#pragma unroll
    for (int qt = 0; qt < 4; ++qt) oacc[dt][qt] = (f32x4){0.f, 0.f, 0.f, 0.f};

  u16* Pw = &Pl[w * 64 * 40];

  for (int ks = 0; ks < 16; ++ks) {
    bf16x8 kf[2][2];
#pragma unroll
    for (int kvt = 0; kvt < 2; ++kvt) {
      int kv = ks * 32 + kvt * 16 + (l & 15);
#pragma unroll
      for (int dc = 0; dc < 2; ++dc) {
        int phys = (dc * 4 + (l >> 4)) ^ (kv & 7);
        kf[kvt][dc] = *(const bf16x8*)&Ke[kv * 64 + phys * 8];
      }
    }
    f32x4 sacc[2][4];
#pragma unroll
    for (int kvt = 0; kvt < 2; ++kvt)
#pragma unroll
      for (int qt = 0; qt < 4; ++qt) {
        f32x4 a = (f32x4){0.f, 0.f, 0.f, 0.f};
        a = __builtin_amdgcn_mfma_f32_16x16x32_bf16(kf[kvt][0], qf[qt][0], a, 0, 0, 0);
        a = __builtin_amdgcn_mfma_f32_16x16x32_bf16(kf[kvt][1], qf[qt][1], a, 0, 0, 0);
        sacc[kvt][qt] = a;
      }
#pragma unroll
    for (int kvt = 0; kvt < 2; ++kvt) {
      f32x4 ev = *(const f32x4*)&extl[ks * 32 + kvt * 16 + (l >> 4) * 4];
#pragma unroll
      for (int qt = 0; qt < 4; ++qt)
#pragma unroll
        for (int r = 0; r < 4; ++r)
          sacc[kvt][qt][r] = fmaf(sacc[kvt][qt][r], 0.125f, ev[r]);
    }
#pragma unroll
    for (int qt = 0; qt < 4; ++qt) {
      float pm = sacc[0][qt][0];
#pragma unroll
      for (int r = 1; r < 4; ++r) pm = fmaxf(pm, sacc[0][qt][r]);
#pragma unroll
      for (int r = 0; r < 4; ++r) pm = fmaxf(pm, sacc[1][qt][r]);
      pm = fmaxf(pm, __shfl_xor(pm, 16));
      pm = fmaxf(pm, __shfl_xor(pm, 32));
      float mnew = fmaxf(mrun[qt], pm);
      float f = __expf(mrun[qt] - mnew);
      mrun[qt] = mnew;
      float lsum = 0.f;
#pragma unroll
      for (int kvt = 0; kvt < 2; ++kvt)
#pragma unroll
        for (int r = 0; r < 4; ++r) {
          float p = __expf(sacc[kvt][qt][r] - mnew);
          sacc[kvt][qt][r] = p;
          lsum += p;
        }
      lsum += __shfl_xor(lsum, 16);
      lsum += __shfl_xor(lsum, 32);
      lrun[qt] = lrun[qt] * f + lsum;
#pragma unroll
      for (int dt = 0; dt < 4; ++dt)
#pragma unroll
        for (int r = 0; r < 4; ++r) oacc[dt][qt][r] *= f;
#pragma unroll
      for (int kvt = 0; kvt < 2; ++kvt) {
        u32 p01 = (u32)f2bf(sacc[kvt][qt][0]) | ((u32)f2bf(sacc[kvt][qt][1]) << 16);
        u32 p23 = (u32)f2bf(sacc[kvt][qt][2]) | ((u32)f2bf(sacc[kvt][qt][3]) << 16);
        u16* pr = Pw + (qt * 16 + (l & 15)) * 40 + kvt * 16 + (l >> 4) * 4;
        *(u32*)pr = p01;
        *(u32*)(pr + 2) = p23;
      }
    }
    bf16x8 vf[4], pf[4];
#pragma unroll
    for (int dt = 0; dt < 4; ++dt) {
      int d = dt * 16 + (l & 15);
      int phys = (ks * 4 + (l >> 4)) ^ (d & 7);
      vf[dt] = *(const bf16x8*)&Vt[d * 512 + phys * 8];
    }
#pragma unroll
    for (int qt = 0; qt < 4; ++qt)
      pf[qt] = *(const bf16x8*)(Pw + (qt * 16 + (l & 15)) * 40 + (l >> 4) * 8);
#pragma unroll
    for (int dt = 0; dt < 4; ++dt)
#pragma unroll
      for (int qt = 0; qt < 4; ++qt)
        oacc[dt][qt] = __builtin_amdgcn_mfma_f32_16x16x32_bf16(vf[dt], pf[qt], oacc[dt][qt], 0, 0, 0);
  }

  float lmax = 0.f;
  u16* Ob = O + (long)(b * 512 + qbase) * C_ + h * 64;
#pragma unroll
  for (int qt = 0; qt < 4; ++qt) {
    float inv = 1.0f / lrun[qt];
    long qoff = (long)(qt * 16 + (l & 15)) * C_;
#pragma unroll
    for (int dt = 0; dt < 4; ++dt) {
      int d = dt * 16 + (l >> 4) * 4;
      float v0 = oacc[dt][qt][0] * inv;
      float v1 = oacc[dt][qt][1] * inv;
      float v2 = oacc[dt][qt][2] * inv;
      float v3 = oacc[dt][qt][3] * inv;
      lmax = fmaxf(fmaxf(lmax, fmaxf(fabsf(v0), fabsf(v1))), fmaxf(fabsf(v2), fabsf(v3)));
      u32 a01 = (u32)f2bf(v0) | ((u32)f2bf(v1) << 16);
      u32 a23 = (u32)f2bf(v2) | ((u32)f2bf(v3) << 16);
      *(u32*)(Ob + qoff + d) = a01;
      *(u32*)(Ob + qoff + d + 2) = a23;
    }
  }
  lmax = wredMax(lmax);
  if (l == 0) redm[w] = lmax;
  __threadfence();
  __syncthreads();
  if (tid == 0) {
    slotAtomicMax(amax, blockIdx.x * 2 + blockIdx.y,
                  fmaxf(fmaxf(redm[0], redm[1]), fmaxf(redm[2], redm[3])));
    gridBarrier(ctr, 256u);
  }
  __syncthreads();
  // in-kernel quant of own O tile: 256 rows x 64 cols
  {
    float s = fmaxf(slotMaxAcq(amax) * (1.0f / 127.0f), 1e-8f);
    float invq = 1.0f / s;
    const long base = (long)(b * 512 + chunk * 256) * C_ + h * 64;
#pragma unroll
    for (int i = 0; i < 8; ++i) {
      int e = (tid + i * 256) * 8;   // 0..131064
      int r = e >> 6, c = e & 63;
      uint4 d = *(const uint4*)(O + base + (long)r * C_ + c);
      u16* el = (u16*)&d;
      uint2 o;
      o.x = (u32)(qi(bf2f(el[0]), invq) & 255) | ((u32)(qi(bf2f(el[1]), invq) & 255) << 8) |
            ((u32)(qi(bf2f(el[2]), invq) & 255) << 16) | ((u32)(qi(bf2f(el[3]), invq) & 255) << 24);
      o.y = (u32)(qi(bf2f(el[4]), invq) & 255) | ((u32)(qi(bf2f(el[5]), invq) & 255) << 8) |
            ((u32)(qi(bf2f(el[6]), invq) & 255) << 16) | ((u32)(qi(bf2f(el[7]), invq) & 255) << 24);
      *(uint2*)(Oq + base + (long)r * C_ + c) = o;
    }
  }
}

// ---------------- int8 MFMA GEMM, BK=128 2-phase ----------------
// EPI: 0 = +bias -> bf16
//      1 = +bias + f32 resid -> bf16 (proj: h)
//      3 = +bias + bf16 resid -> f32 (final output)
template <int BM, int BN, int EPI, bool SWZ>
__global__ __launch_bounds__(256) void k_gemmq(
    const signed char* __restrict__ A, int lda,
    const signed char* __restrict__ Bm, int ldb,
    const float* __restrict__ bias,
    void* __restrict__ Cp, int ldc,
    int M, int N, int K,
    const void* __restrict__ resid,
    u32* __restrict__ amaxOut,
    const u32* __restrict__ amaxA, const u32* __restrict__ amaxB) {
  constexpr int BK = 128;
  constexpr int MF = (BM / 2) / 16;
  constexpr int NF = (BN / 2) / 16;
  constexpr int NLD = BM / 32 + BN / 32;
  __shared__ __align__(16) signed char As[2][BM * BK];
  __shared__ __align__(16) signed char Bs[2][BN * BK];
  const int tid = threadIdx.x;
  const int wid = tid >> 6, lane = tid & 63;
  const int wr = wid >> 1, wc = wid & 1;

  float sa = fmaxf(slotMax(amaxA) * (1.0f / 127.0f), 1e-8f);
  float sb = fmaxf(slotMax(amaxB) * (1.0f / 127.0f), 1e-8f);
  const float sAB = sa * sb;

  int bx = blockIdx.x, by = blockIdx.y;
  if (SWZ) {
    int gx = gridDim.x;
    int nwg = gx * gridDim.y;
    int bid = by * gx + bx;
    int cpx = nwg >> 3;
    int swz = (bid & 7) * cpx + (bid >> 3);
    bx = swz % gx;
    by = swz / gx;
  }

  const signed char* Ab = A + (long)by * BM * lda;
  const signed char* Bb = Bm + (long)bx * BN * ldb;

  i32x4 acc[MF][NF];
#pragma unroll
  for (int m = 0; m < MF; m++)
#pragma unroll
    for (int n = 0; n < NF; n++) acc[m][n] = (i32x4){0, 0, 0, 0};

  const int lr = lane & 15;
  const int l8 = lane >> 3;
  const int s8 = (lane & 7) ^ l8;
  const long aoff = (long)l8 * lda + s8 * 16;
  const long boff = (long)l8 * ldb + s8 * 16;

  auto stageAB = [&](int buf, int k0) {
#pragma unroll
    for (int i = 0; i < BM / 32; ++i) {
      int R0 = wid * (BM / 4) + i * 8;
      gload16(Ab + (long)R0 * lda + k0 + aoff, &As[buf][R0 * BK]);
    }
#pragma unroll
    for (int i = 0; i < BN / 32; ++i) {
      int R0 = wid * (BN / 4) + i * 8;
      gload16(Bb + (long)R0 * ldb + k0 + boff, &Bs[buf][R0 * BK]);
    }
  };

  auto waitCounted = [&]() {
    if constexpr (NLD == 8) {
      asm volatile("s_waitcnt vmcnt(8)" ::: "memory");
    } else if constexpr (NLD == 6) {
      asm volatile("s_waitcnt vmcnt(6)" ::: "memory");
    } else {
      asm volatile("s_waitcnt vmcnt(4)" ::: "memory");
    }
  };

  auto computeK = [&](int buf) {
#pragma unroll
    for (int kk = 0; kk < 2; ++kk) {
      const int sl = (kk << 2) + (lane >> 4);
      const int sf = (sl ^ (lr & 7)) << 4;
      i32x4 af[MF], bfr[NF];
#pragma unroll
      for (int m = 0; m < MF; m++)
        af[m] = *(const i32x4*)&As[buf][(wr * (BM / 2) + m * 16 + lr) * BK + sf];
#pragma unroll
      for (int n = 0; n < NF; n++)
        bfr[n] = *(const i32x4*)&Bs[buf][(wc * (BN / 2) + n * 16 + lr) * BK + sf];
      __builtin_amdgcn_s_setprio(1);
#pragma unroll
      for (int m = 0; m < MF; m++)
#pragma unroll
        for (int n = 0; n < NF; n++)
          acc[m][n] = __builtin_amdgcn_mfma_i32_16x16x64_i8(af[m], bfr[n], acc[m][n], 0, 0, 0);
      __builtin_amdgcn_s_setprio(0);
    }
  };

  const int nt = K / BK;
  stageAB(0, 0);
  int cur = 0;
  for (int t = 0; t < nt; ++t) {
    if (t + 1 < nt) {
      stageAB(cur ^ 1, (t + 1) * BK);
      waitCounted();
    } else {
      asm volatile("s_waitcnt vmcnt(0)" ::: "memory");
    }
    __builtin_amdgcn_s_barrier();
    computeK(cur);
    if (t + 1 < nt)
      __builtin_amdgcn_s_barrier();
    cur ^= 1;
  }

  const int rowBase = by * BM + wr * (BM / 2);
  const int colBase = bx * BN + wc * (BN / 2);
#pragma unroll
  for (int m = 0; m < MF; m++) {
    int row0 = rowBase + m * 16 + (lane >> 4) * 4;
#pragma unroll
    for (int n = 0; n < NF; n++) {
      int col = colBase + n * 16 + lr;
      float bs = bias[col];
#pragma unroll
      for (int j = 0; j < 4; j++) {
        int row = row0 + j;
        long idx = (long)row * ldc + col;
        float v = (float)acc[m][n][j] * sAB;
        if (EPI == 0) {
          ((u16*)Cp)[idx] = f2bf(v + bs);
        } else if (EPI == 1) {
          ((u16*)Cp)[idx] = f2bf(v + bs + ((const float*)resid)[idx]);
        } else if (EPI == 3) {
          ((float*)Cp)[idx] = v + bs + bf2f(((const u16*)resid)[idx]);
        }
      }
    }
  }
}

// ---------------- 256x256 8-phase int8 GEMM (w1) + in-kernel y1 quant ----------------
// grid = 256 blocks, 1 block/CU (128KB LDS) -> co-resident; counted vmcnt in
// K-loop; after epilogue, grid-barrier then quantize own 256x256 tile.
__global__ __launch_bounds__(512, 1) void k_gemmq8(
    const signed char* __restrict__ A, int lda,
    const signed char* __restrict__ Bm, int ldb,
    const float* __restrict__ bias,
    u16* __restrict__ Cp, int ldc,
    int K,
    u32* __restrict__ amaxOut,
    const u32* __restrict__ amaxA, const u32* __restrict__ amaxB,
    signed char* __restrict__ Cq, u32* __restrict__ ctr) {
  __shared__ __align__(16) signed char As[2][256 * 128];
  __shared__ __align__(16) signed char Bs[2][256 * 128];
  const int tid = threadIdx.x;
  const int wid = tid >> 6, lane = tid & 63;
  const int wr = wid >> 2, wc = wid & 3;
  const int lr = lane & 15;

  float sa = fmaxf(slotMax(amaxA) * (1.0f / 127.0f), 1e-8f);
  float sb = fmaxf(slotMax(amaxB) * (1.0f / 127.0f), 1e-8f);
  const float sAB = sa * sb;

  int bx = blockIdx.x, by = blockIdx.y;
  {
    int bid = by * 16 + bx;
    int swz = (bid & 7) * 32 + (bid >> 3);
    bx = swz & 15;
    by = swz >> 4;
  }
  const signed char* Ab = A + (long)by * 256 * lda;
  const signed char* Bb = Bm + (long)bx * 256 * ldb;

  i32x4 acc[8][4];
#pragma unroll
  for (int m = 0; m < 8; m++)
#pragma unroll
    for (int n = 0; n < 4; n++) acc[m][n] = (i32x4){0, 0, 0, 0};

  const int l8 = lane >> 3;
  const int s8 = (lane & 7) ^ l8;
  const long aoff = (long)l8 * lda + s8 * 16;
  const long boff = (long)l8 * ldb + s8 * 16;

  auto stageHalf = [&](int buf, int kt, int h) {
    int k0 = kt * 128;
    if (h < 2) {
      int R0 = h * 128 + wid * 16;
      gload16(Ab + (long)R0 * lda + k0 + aoff, &As[buf][R0 * 128]);
      gload16(Ab + (long)(R0 + 8) * lda + k0 + aoff, &As[buf][(R0 + 8) * 128]);
    } else {
      int R0 = (h - 2) * 128 + wid * 16;
      gload16(Bb + (long)R0 * ldb + k0 + boff, &Bs[buf][R0 * 128]);
      gload16(Bb + (long)(R0 + 8) * ldb + k0 + boff, &Bs[buf][(R0 + 8) * 128]);
    }
  };

  const int nt = K / 128;
#define PHASE(BUF, MH, KS, STAGESTMT)                                              \
  {                                                                                \
    const int slotl = (KS) * 4 + (lane >> 4);                                      \
    i32x4 af[4], bfr[4];                                                           \
    _Pragma("unroll") for (int i = 0; i < 4; ++i) {                                \
      int row = wr * 128 + ((MH) * 4 + i) * 16 + lr;                               \
      af[i] = *(const i32x4*)&As[BUF][row * 128 + ((slotl ^ (row & 7)) << 4)];     \
    }                                                                              \
    _Pragma("unroll") for (int n = 0; n < 4; ++n) {                                \
      int row = wc * 64 + n * 16 + lr;                                             \
      bfr[n] = *(const i32x4*)&Bs[BUF][row * 128 + ((slotl ^ (row & 7)) << 4)];    \
    }                                                                              \
    STAGESTMT;                                                                     \
    __builtin_amdgcn_s_barrier();                                                  \
    __builtin_amdgcn_s_setprio(1);                                                 \
    _Pragma("unroll") for (int i = 0; i < 4; ++i)                                  \
      _Pragma("unroll") for (int n = 0; n < 4; ++n)                                \
        acc[(MH) * 4 + i][n] =                                                     \
            __builtin_amdgcn_mfma_i32_16x16x64_i8(af[i], bfr[n], acc[(MH) * 4 + i][n], 0, 0, 0); \
    __builtin_amdgcn_s_setprio(0);                                                 \
    __builtin_amdgcn_s_barrier();                                                  \
  }

  stageHalf(0, 0, 0);
  stageHalf(0, 0, 2);
  stageHalf(0, 0, 3);
  stageHalf(0, 0, 1);

  int cur = 0;
  for (int t = 0; t < nt; ++t) {
    const bool stg = (t + 1 < nt);
    const int nb = cur ^ 1;
    const int tn = t + 1;
    asm volatile("s_waitcnt vmcnt(2)" ::: "memory");
    __builtin_amdgcn_s_barrier();
    PHASE(cur, 0, 0, { if (stg) stageHalf(nb, tn, 0); })
    PHASE(cur, 0, 1, { if (stg) stageHalf(nb, tn, 2); })
    if (stg) {
      asm volatile("s_waitcnt vmcnt(4)" ::: "memory");
    } else {
      asm volatile("s_waitcnt vmcnt(0)" ::: "memory");
    }
    __builtin_amdgcn_s_barrier();
    PHASE(cur, 1, 0, { if (stg) stageHalf(nb, tn, 3); })
    PHASE(cur, 1, 1, { if (stg) stageHalf(nb, tn, 1); })
    cur = nb;
  }
#undef PHASE

  const int rowBase = by * 256 + wr * 128;
  const int colBase = bx * 256 + wc * 64;
  float lmax = 0.f;
#pragma unroll
  for (int m = 0; m < 8; m++) {
    int row0 = rowBase + m * 16 + (lane >> 4) * 4;
#pragma unroll
    for (int n = 0; n < 4; n++) {
      int col = colBase + n * 16 + lr;
      float bs = bias[col];
#pragma unroll
      for (int j = 0; j < 4; j++) {
        long idx = (long)(row0 + j) * ldc + col;
        float v = gelu1((float)acc[m][n][j] * sAB + bs);
        lmax = fmaxf(fmaxf(lmax, v), 0.0f - v);
        Cp[idx] = f2bf(v);
      }
    }
  }
  {
    __shared__ float redm[8];
    float wm = wredMax(lmax);
    if (lane == 0) redm[wid] = wm;
    __threadfence();
    __syncthreads();
    if (tid == 0) {
      float bm = redm[0];
#pragma unroll
      for (int i = 1; i < 8; ++i) bm = fmaxf(bm, redm[i]);
      slotAtomicMax(amaxOut, blockIdx.y * gridDim.x + blockIdx.x, bm);
      gridBarrier(ctr, 256u);
    }
    __syncthreads();
  }
  // in-kernel quant of own 256x256 tile
  {
    float s = fmaxf(slotMaxAcq(amaxOut) * (1.0f / 127.0f), 1e-8f);
    float invq = 1.0f / s;
    const long base = (long)(by * 256) * ldc + bx * 256;
#pragma unroll
    for (int i = 0; i < 16; ++i) {
      int e = (tid + i * 512) * 8;   // 0..524280
      int r = e >> 8, c = e & 255;
      uint4 d = *(const uint4*)(Cp + base + (long)r * ldc + c);
      u16* el = (u16*)&d;
      uint2 o;
      o.x = (u32)(qi(bf2f(el[0]), invq) & 255) | ((u32)(qi(bf2f(el[1]), invq) & 255) << 8) |
            ((u32)(qi(bf2f(el[2]), invq) & 255) << 16) | ((u32)(qi(bf2f(el[3]), invq) & 255) << 24);
      o.y = (u32)(qi(bf2f(el[4]), invq) & 255) | ((u32)(qi(bf2f(el[5]), invq) & 255) << 8) |
            ((u32)(qi(bf2f(el[6]), invq) & 255) << 16) | ((u32)(qi(bf2f(el[7]), invq) & 255) << 24);
      *(uint2*)(Cq + base + (long)r * ldc + c) = o;
    }
  }
}

// ---------------- host ----------------
extern "C" void kernel_launch(void* const* d_in, const int* in_sizes, int n_in,
                              void* d_out, int out_size, void* d_ws, size_t ws_size,
                              hipStream_t stream) {
  const float* hidden = (const float*)d_in[0];
  const float* mask = (const float*)d_in[1];
  const float* ln1g = (const float*)d_in[2];
  const float* ln1b = (const float*)d_in[3];
  const float* ln2g = (const float*)d_in[4];
  const float* ln2b = (const float*)d_in[5];
  const float* w_qkv = (const float*)d_in[6];
  const float* b_qkv = (const float*)d_in[7];
  const float* w_out = (const float*)d_in[8];
  const float* b_out = (const float*)d_in[9];
  const float* w1 = (const float*)d_in[10];
  const float* b1 = (const float*)d_in[11];
  const float* w2 = (const float*)d_in[12];
  const float* b2 = (const float*)d_in[13];

  char* ws = (char*)d_ws;
  u32* sc = (u32*)ws;
  // slots: 8 x 1024 u32; counters at sc+8192 (attn) and sc+8208 (w1)
  u32* ctrA = sc + 8192;
  u32* ctrW = sc + 8208;
  const long MB = 1024 * 1024;
  signed char* wq_qkv = (signed char*)(ws + 1 * MB);
  signed char* wq_out = (signed char*)(ws + 4 * MB);
  signed char* wq_w1  = (signed char*)(ws + 6 * MB);
  signed char* wq_w2  = (signed char*)(ws + 10 * MB);
  signed char* xq     = (signed char*)(ws + 14 * MB);
  u16* x1             = (u16*)(ws + 18 * MB);
  signed char* Oq     = (signed char*)(ws + 26 * MB);
  u16* O              = (u16*)(ws + 30 * MB);
  u16* qkv            = (u16*)(ws + 38 * MB);
  u16* hbuf           = (u16*)(ws + 62 * MB);   // h in bf16 (8 MB)
  u16* y1             = (u16*)(ws + 78 * MB);
  signed char* y1q    = (signed char*)(ws + 110 * MB);

  k_init<<<34, 256, 0, stream>>>(sc);

  // fused: weight absmax (blocks 0-511) + LN1 (blocks 512-4607)
  k_pre1<<<512 + BT, 256, 0, stream>>>(
      w_qkv, 3 * C_ * C_ / 4, w_out, C_ * C_ / 4, w1, I_ * C_ / 4, w2, C_ * I_ / 4, sc,
      hidden, ln1g, ln1b, x1, sc + 4 * 1024);

  // fused: weight quant (blocks 0-511) + x1 quant (blocks 512-1023)
  k_pre2<<<1024, 256, 0, stream>>>(
      w_qkv, wq_qkv, 3 * C_ * C_ / 4, w_out, wq_out, C_ * C_ / 4,
      w1, wq_w1, I_ * C_ / 4, w2, wq_w2, C_ * I_ / 4, sc,
      x1, xq, BT * C_ / 8, sc + 4 * 1024);

  // qkv = (xq . wq_qkv^T)*s + b -> bf16 [4096,3072]
  k_gemmq<128, 128, 0, true><<<dim3(24, 32), 256, 0, stream>>>(
      xq, C_, wq_qkv, C_, b_qkv, qkv, 3 * C_,
      BT, 3 * C_, C_, nullptr, nullptr, sc + 4 * 1024, sc + 0 * 1024);

  // fused attention + in-kernel O quant (grid 256, co-resident)
  k_attn<<<dim3(NH, 2), 256, 0, stream>>>(qkv, mask, O, sc + 5 * 1024, Oq, ctrA);

  // h = hidden + (Oq . wq_out^T)*s + b -> bf16 hbuf
  k_gemmq<64, 64, 1, true><<<dim3(16, 64), 256, 0, stream>>>(
      Oq, C_, wq_out, C_, b_out, hbuf, C_,
      BT, C_, C_, hidden, nullptr, sc + 5 * 1024, sc + 1 * 1024);

  // LN2 (bf16 in/out) + quant
  k_lnb<<<BT, 256, 0, stream>>>(hbuf, ln2g, ln2b, x1, sc + 6 * 1024);
  k_quant_b8<<<512, 256, 0, stream>>>(x1, xq, BT * C_ / 8, sc + 6 * 1024);

  // y1 = gelu((xq . wq_w1^T)*s + b1) -> bf16 + in-kernel y1 quant (grid 256)
  k_gemmq8<<<dim3(16, 16), 512, 0, stream>>>(
      xq, C_, wq_w1, C_, b1, y1, I_, C_,
      sc + 7 * 1024, sc + 6 * 1024, sc + 2 * 1024, y1q, ctrW);

  // out = (y1q . wq_w2^T)*s + b2 + h(bf16) -> f32 d_out
  k_gemmq<64, 64, 3, true><<<dim3(16, 64), 256, 0, stream>>>(
      y1q, I_, wq_w2, I_, b2, d_out, C_,
      BT, C_, I_, hbuf, nullptr, sc + 7 * 1024, sc + 3 * 1024);
}

// Round 25
// 238.642 us; speedup vs baseline: 1.5059x; 1.5059x over previous
//
#include <hip/hip_runtime.h>

typedef __attribute__((ext_vector_type(8))) short bf16x8;
typedef __attribute__((ext_vector_type(4))) float f32x4;
typedef __attribute__((ext_vector_type(4))) int i32x4;
typedef unsigned short u16;
typedef unsigned int u32;

#define B_ 8
#define T_ 512
#define C_ 1024
#define I_ 4096
#define H_ 16
#define Dh_ 64
#define BT (B_*T_)
#define NH (B_*H_)

// ---------------- helpers ----------------
__device__ __forceinline__ float bf2f(u16 u) {
  return __uint_as_float(((u32)u) << 16);
}
__device__ __forceinline__ u16 f2bf(float f) {
  u32 u = __float_as_uint(f);
  u32 r = u + 0x7FFFu + ((u >> 16) & 1u);
  return (u16)(r >> 16);
}
__device__ __forceinline__ float wredMax(float v) {
#pragma unroll
  for (int o = 32; o; o >>= 1) v = fmaxf(v, __shfl_xor(v, o));
  return v;
}
__device__ __forceinline__ float wredSum(float v) {
#pragma unroll
  for (int o = 32; o; o >>= 1) v += __shfl_xor(v, o);
  return v;
}
// 64-slot strided max array (one 64B line per slot).
__device__ __forceinline__ void slotAtomicMax(u32* arr, int bid, float bm) {
  u32 b = __float_as_uint(bm);
  volatile u32* p = arr + ((bid & 63) << 4);
  if (b > *p) atomicMax((u32*)p, b);
}
__device__ __forceinline__ float slotMax(const u32* __restrict__ arr) {
  float m = 0.f;
#pragma unroll
  for (int i = 0; i < 64; ++i) m = fmaxf(m, __uint_as_float(arr[i << 4]));
  return m;
}
__device__ __forceinline__ void gload16(const void* g, void* l) {
  __builtin_amdgcn_global_load_lds((const __attribute__((address_space(1))) void*)g,
                                   (__attribute__((address_space(3))) void*)l, 16, 0, 0);
}
__device__ __forceinline__ int qi(float v, float inv) {
  return (int)fminf(fmaxf(rintf(v * inv), -127.f), 127.f);
}
__device__ __forceinline__ float gelu1(float v) {
  float x2 = v * v;
  float e = __expf(v * fmaf(-0.0713548755f, x2, -1.5957691216f));
  return v * __builtin_amdgcn_rcpf(1.0f + e);
}

// ---------------- small kernels ----------------
__global__ void k_init(u32* s) {
  int i = blockIdx.x * 256 + threadIdx.x;
  if (i < 8192) s[i] = 0u;
}

// fused: blocks [0,512) = absmax of 4 weight arrays -> slots 0..3
//        blocks [512, 512+BT) = LayerNorm1 (f32 in, bf16 out) -> slot arr
__global__ __launch_bounds__(256) void k_pre1(
    const float* __restrict__ p0, int n0,
    const float* __restrict__ p1, int n1,
    const float* __restrict__ p2, int n2,
    const float* __restrict__ p3, int n3,
    u32* __restrict__ scw,
    const float* __restrict__ x, const float* __restrict__ g,
    const float* __restrict__ b, u16* __restrict__ y,
    u32* __restrict__ arr) {
  const int t = threadIdx.x;
  if (blockIdx.x < 512) {
    int stride = 512 * 256;
    int gid = blockIdx.x * 256 + t;
    float m0 = 0.f, m1 = 0.f, m2 = 0.f, m3 = 0.f;
    for (int i = gid; i < n0; i += stride) {
      float4 v = ((const float4*)p0)[i];
      m0 = fmaxf(m0, fmaxf(fmaxf(fabsf(v.x), fabsf(v.y)), fmaxf(fabsf(v.z), fabsf(v.w))));
    }
    for (int i = gid; i < n1; i += stride) {
      float4 v = ((const float4*)p1)[i];
      m1 = fmaxf(m1, fmaxf(fmaxf(fabsf(v.x), fabsf(v.y)), fmaxf(fabsf(v.z), fabsf(v.w))));
    }
    for (int i = gid; i < n2; i += stride) {
      float4 v = ((const float4*)p2)[i];
      m2 = fmaxf(m2, fmaxf(fmaxf(fabsf(v.x), fabsf(v.y)), fmaxf(fabsf(v.z), fabsf(v.w))));
    }
    for (int i = gid; i < n3; i += stride) {
      float4 v = ((const float4*)p3)[i];
      m3 = fmaxf(m3, fmaxf(fmaxf(fabsf(v.x), fabsf(v.y)), fmaxf(fabsf(v.z), fabsf(v.w))));
    }
    m0 = wredMax(m0); m1 = wredMax(m1); m2 = wredMax(m2); m3 = wredMax(m3);
    __shared__ float red4[4][4];
    int wid = t >> 6, lane = t & 63;
    if (lane == 0) { red4[wid][0] = m0; red4[wid][1] = m1; red4[wid][2] = m2; red4[wid][3] = m3; }
    __syncthreads();
    if (t < 4) {
      int j = t;
      float bm = fmaxf(fmaxf(red4[0][j], red4[1][j]), fmaxf(red4[2][j], red4[3][j]));
      slotAtomicMax(scw + j * 1024, blockIdx.x, bm);
    }
  } else {
    int row = blockIdx.x - 512;
    float4 v = ((const float4*)(x + (long)row * C_))[t];
    float s1 = v.x + v.y + v.z + v.w;
    float s2 = v.x * v.x + v.y * v.y + v.z * v.z + v.w * v.w;
    s1 = wredSum(s1);
    s2 = wredSum(s2);
    __shared__ float red[8];
    int wid = t >> 6, lane = t & 63;
    if (lane == 0) { red[wid] = s1; red[4 + wid] = s2; }
    __syncthreads();
    s1 = red[0] + red[1] + red[2] + red[3];
    s2 = red[4] + red[5] + red[6] + red[7];
    float mean = s1 * (1.0f / C_);
    float var = s2 * (1.0f / C_) - mean * mean;
    float inv = rsqrtf(var + 1e-5f);
    float4 gv = ((const float4*)g)[t];
    float4 bv = ((const float4*)b)[t];
    float4 o;
    o.x = (v.x - mean) * inv * gv.x + bv.x;
    o.y = (v.y - mean) * inv * gv.y + bv.y;
    o.z = (v.z - mean) * inv * gv.z + bv.z;
    o.w = (v.w - mean) * inv * gv.w + bv.w;
    ushort4 ob;
    ob.x = f2bf(o.x); ob.y = f2bf(o.y); ob.z = f2bf(o.z); ob.w = f2bf(o.w);
    ((ushort4*)(y + (long)row * C_))[t] = ob;
    float m = fmaxf(fmaxf(fabsf(o.x), fabsf(o.y)), fmaxf(fabsf(o.z), fabsf(o.w)));
    m = wredMax(m);
    __syncthreads();
    if (lane == 0) red[wid] = m;
    __syncthreads();
    if (t == 0) {
      float bm = fmaxf(fmaxf(red[0], red[1]), fmaxf(red[2], red[3]));
      slotAtomicMax(arr, row, bm);
    }
  }
}

// fused: blocks [0,512) = quantize 4 weight arrays -> i8 (scales slots 0..3)
//        blocks [512,1024) = quantize x1 bf16 -> i8 (scale arrX)
__global__ __launch_bounds__(256) void k_pre2(
    const float* __restrict__ p0, signed char* __restrict__ q0, int n0,
    const float* __restrict__ p1, signed char* __restrict__ q1, int n1,
    const float* __restrict__ p2, signed char* __restrict__ q2, int n2,
    const float* __restrict__ p3, signed char* __restrict__ q3, int n3,
    const u32* __restrict__ scw,
    const u16* __restrict__ xb, signed char* __restrict__ xq, int n8,
    const u32* __restrict__ arrX) {
  const int t = threadIdx.x;
  if (blockIdx.x < 512) {
    int stride = 512 * 256;
    int gid = blockIdx.x * 256 + t;
#define QLOOP(p, q, n, slot)                                                        \
    {                                                                               \
      float s = fmaxf(slotMax(scw + slot * 1024) * (1.0f / 127.0f), 1e-8f);         \
      float inv = 1.0f / s;                                                         \
      for (int i = gid; i < n; i += stride) {                                       \
        float4 v = ((const float4*)p)[i];                                           \
        u32 pk = (u32)(qi(v.x, inv) & 255) | ((u32)(qi(v.y, inv) & 255) << 8) |     \
                 ((u32)(qi(v.z, inv) & 255) << 16) | ((u32)(qi(v.w, inv) & 255) << 24); \
        ((u32*)q)[i] = pk;                                                          \
      }                                                                             \
    }
    QLOOP(p0, q0, n0, 0)
    QLOOP(p1, q1, n1, 1)
    QLOOP(p2, q2, n2, 2)
    QLOOP(p3, q3, n3, 3)
#undef QLOOP
  } else {
    float s = fmaxf(slotMax(arrX) * (1.0f / 127.0f), 1e-8f);
    float inv = 1.0f / s;
    int stride = 512 * 256;
    for (int i = (blockIdx.x - 512) * 256 + t; i < n8; i += stride) {
      uint4 d = ((const uint4*)xb)[i];
      u16* e = (u16*)&d;
      uint2 o;
      o.x = (u32)(qi(bf2f(e[0]), inv) & 255) | ((u32)(qi(bf2f(e[1]), inv) & 255) << 8) |
            ((u32)(qi(bf2f(e[2]), inv) & 255) << 16) | ((u32)(qi(bf2f(e[3]), inv) & 255) << 24);
      o.y = (u32)(qi(bf2f(e[4]), inv) & 255) | ((u32)(qi(bf2f(e[5]), inv) & 255) << 8) |
            ((u32)(qi(bf2f(e[6]), inv) & 255) << 16) | ((u32)(qi(bf2f(e[7]), inv) & 255) << 24);
      ((uint2*)xq)[i] = o;
    }
  }
}

__global__ __launch_bounds__(256) void k_quant_b8(const u16* __restrict__ x, signed char* __restrict__ q,
                                                  int n8, const u32* __restrict__ arr) {
  float s = fmaxf(slotMax(arr) * (1.0f / 127.0f), 1e-8f);
  float inv = 1.0f / s;
  int stride = gridDim.x * blockDim.x;
  for (int i = blockIdx.x * blockDim.x + threadIdx.x; i < n8; i += stride) {
    uint4 d = ((const uint4*)x)[i];
    u16* e = (u16*)&d;
    uint2 o;
    o.x = (u32)(qi(bf2f(e[0]), inv) & 255) | ((u32)(qi(bf2f(e[1]), inv) & 255) << 8) |
          ((u32)(qi(bf2f(e[2]), inv) & 255) << 16) | ((u32)(qi(bf2f(e[3]), inv) & 255) << 24);
    o.y = (u32)(qi(bf2f(e[4]), inv) & 255) | ((u32)(qi(bf2f(e[5]), inv) & 255) << 8) |
          ((u32)(qi(bf2f(e[6]), inv) & 255) << 16) | ((u32)(qi(bf2f(e[7]), inv) & 255) << 24);
    ((uint2*)q)[i] = o;
  }
}

// LayerNorm over bf16 input rows (C=1024) -> bf16 out + slot absmax (LN2)
__global__ __launch_bounds__(256) void k_lnb(const u16* __restrict__ x, const float* __restrict__ g,
                                             const float* __restrict__ b, u16* __restrict__ y,
                                             u32* __restrict__ arr) {
  int row = blockIdx.x;
  int t = threadIdx.x;
  ushort4 xb = ((const ushort4*)(x + (long)row * C_))[t];
  float4 v;
  v.x = bf2f(xb.x); v.y = bf2f(xb.y); v.z = bf2f(xb.z); v.w = bf2f(xb.w);
  float s1 = v.x + v.y + v.z + v.w;
  float s2 = v.x * v.x + v.y * v.y + v.z * v.z + v.w * v.w;
  s1 = wredSum(s1);
  s2 = wredSum(s2);
  __shared__ float red[8];
  int wid = t >> 6, lane = t & 63;
  if (lane == 0) { red[wid] = s1; red[4 + wid] = s2; }
  __syncthreads();
  s1 = red[0] + red[1] + red[2] + red[3];
  s2 = red[4] + red[5] + red[6] + red[7];
  float mean = s1 * (1.0f / C_);
  float var = s2 * (1.0f / C_) - mean * mean;
  float inv = rsqrtf(var + 1e-5f);
  float4 gv = ((const float4*)g)[t];
  float4 bv = ((const float4*)b)[t];
  float4 o;
  o.x = (v.x - mean) * inv * gv.x + bv.x;
  o.y = (v.y - mean) * inv * gv.y + bv.y;
  o.z = (v.z - mean) * inv * gv.z + bv.z;
  o.w = (v.w - mean) * inv * gv.w + bv.w;
  ushort4 ob;
  ob.x = f2bf(o.x); ob.y = f2bf(o.y); ob.z = f2bf(o.z); ob.w = f2bf(o.w);
  ((ushort4*)(y + (long)row * C_))[t] = ob;
  float m = fmaxf(fmaxf(fabsf(o.x), fabsf(o.y)), fmaxf(fabsf(o.z), fabsf(o.w)));
  m = wredMax(m);
  __syncthreads();
  if (lane == 0) red[wid] = m;
  __syncthreads();
  if (t == 0) {
    float bm = fmaxf(fmaxf(red[0], red[1]), fmaxf(red[2], red[3]));
    slotAtomicMax(arr, row, bm);
  }
}

// ---------------- fused attention ----------------
__global__ __launch_bounds__(256, 1) void k_attn(
    const u16* __restrict__ qkv, const float* __restrict__ mask,
    u16* __restrict__ O, u32* __restrict__ amax) {
  __shared__ u16 Ke[512 * 64];
  __shared__ u16 Vt[64 * 512];
  __shared__ u16 Pl[4 * 64 * 40];
  __shared__ float extl[512];
  __shared__ float redm[4];
  const int tid = threadIdx.x;
  const int w = tid >> 6, l = tid & 63;
  const int head = blockIdx.x;
  const int chunk = blockIdx.y;
  const int b = head >> 4, h = head & 15;
  const long rowbase = (long)(b * 512) * (3 * C_);

  {
    const u16* Kg = qkv + rowbase + C_ + h * 64;
    int lr8 = l >> 3;
    int ls = (l & 7) ^ lr8;
    const long koff = (long)lr8 * (3 * C_) + ls * 8;
#pragma unroll
    for (int i = 0; i < 16; ++i) {
      int r0 = w * 128 + i * 8;
      gload16(Kg + (long)r0 * (3 * C_) + koff, &Ke[r0 * 64]);
    }
  }
  {
    const u16* Vg = qkv + rowbase + 2 * C_ + h * 64;
    int kvl = tid & 31;
    int d0 = (tid >> 5) * 8;
#pragma unroll 4
    for (int i = 0; i < 16; ++i) {
      int kv = i * 32 + kvl;
      uint4 t4 = *(const uint4*)(Vg + (long)kv * (3 * C_) + d0);
      u16* tv = (u16*)&t4;
      int slot = kv >> 3, within = kv & 7;
#pragma unroll
      for (int j = 0; j < 8; ++j) {
        int d = d0 + j;
        Vt[d * 512 + ((slot ^ (d & 7)) << 3) + within] = tv[j];
      }
    }
  }
  {
    const float* mb = mask + b * 512;
    extl[tid] = (1.0f - mb[tid]) * -10000.0f;
    extl[tid + 256] = (1.0f - mb[tid + 256]) * -10000.0f;
  }
  const int qbase = chunk * 256 + w * 64;
  bf16x8 qf[4][2];
  {
    const u16* Qg = qkv + rowbase + h * 64;
#pragma unroll
    for (int qt = 0; qt < 4; ++qt)
#pragma unroll
      for (int dc = 0; dc < 2; ++dc)
        qf[qt][dc] = *(const bf16x8*)(Qg + (long)(qbase + qt * 16 + (l & 15)) * (3 * C_) + dc * 32 + (l >> 4) * 8);
  }
  __syncthreads();

  f32x4 oacc[4][4];
  float mrun[4], lrun[4];
#pragma unroll
  for (int qt = 0; qt < 4; ++qt) { mrun[qt] = -3.0e38f; lrun[qt] = 0.f; }
#pragma unroll
  for (int dt = 0; dt < 4; ++dt)
#pragma unroll
    for (int qt = 0; qt < 4; ++qt) oacc[dt][qt] = (f32x4){0.f, 0.f, 0.f, 0.f};

  u16* Pw = &Pl[w * 64 * 40];

  for (int ks = 0; ks < 16; ++ks) {
    bf16x8 kf[2][2];
#pragma unroll
    for (int kvt = 0; kvt < 2; ++kvt) {
      int kv = ks * 32 + kvt * 16 + (l & 15);
#pragma unroll
      for (int dc = 0; dc < 2; ++dc) {
        int phys = (dc * 4 + (l >> 4)) ^ (kv & 7);
        kf[kvt][dc] = *(const bf16x8*)&Ke[kv * 64 + phys * 8];
      }
    }
    f32x4 sacc[2][4];
#pragma unroll
    for (int kvt = 0; kvt < 2; ++kvt)
#pragma unroll
      for (int qt = 0; qt < 4; ++qt) {
        f32x4 a = (f32x4){0.f, 0.f, 0.f, 0.f};
        a = __builtin_amdgcn_mfma_f32_16x16x32_bf16(kf[kvt][0], qf[qt][0], a, 0, 0, 0);
        a = __builtin_amdgcn_mfma_f32_16x16x32_bf16(kf[kvt][1], qf[qt][1], a, 0, 0, 0);
        sacc[kvt][qt] = a;
      }
#pragma unroll
    for (int kvt = 0; kvt < 2; ++kvt) {
      f32x4 ev = *(const f32x4*)&extl[ks * 32 + kvt * 16 + (l >> 4) * 4];
#pragma unroll
      for (int qt = 0; qt < 4; ++qt)
#pragma unroll
        for (int r = 0; r < 4; ++r)
          sacc[kvt][qt][r] = fmaf(sacc[kvt][qt][r], 0.125f, ev[r]);
    }
#pragma unroll
    for (int qt = 0; qt < 4; ++qt) {
      float pm = sacc[0][qt][0];
#pragma unroll
      for (int r = 1; r < 4; ++r) pm = fmaxf(pm, sacc[0][qt][r]);
#pragma unroll
      for (int r = 0; r < 4; ++r) pm = fmaxf(pm, sacc[1][qt][r]);
      pm = fmaxf(pm, __shfl_xor(pm, 16));
      pm = fmaxf(pm, __shfl_xor(pm, 32));
      float mnew = fmaxf(mrun[qt], pm);
      float f = __expf(mrun[qt] - mnew);
      mrun[qt] = mnew;
      float lsum = 0.f;
#pragma unroll
      for (int kvt = 0; kvt < 2; ++kvt)
#pragma unroll
        for (int r = 0; r < 4; ++r) {
          float p = __expf(sacc[kvt][qt][r] - mnew);
          sacc[kvt][qt][r] = p;
          lsum += p;
        }
      lsum += __shfl_xor(lsum, 16);
      lsum += __shfl_xor(lsum, 32);
      lrun[qt] = lrun[qt] * f + lsum;
#pragma unroll
      for (int dt = 0; dt < 4; ++dt)
#pragma unroll
        for (int r = 0; r < 4; ++r) oacc[dt][qt][r] *= f;
#pragma unroll
      for (int kvt = 0; kvt < 2; ++kvt) {
        u32 p01 = (u32)f2bf(sacc[kvt][qt][0]) | ((u32)f2bf(sacc[kvt][qt][1]) << 16);
        u32 p23 = (u32)f2bf(sacc[kvt][qt][2]) | ((u32)f2bf(sacc[kvt][qt][3]) << 16);
        u16* pr = Pw + (qt * 16 + (l & 15)) * 40 + kvt * 16 + (l >> 4) * 4;
        *(u32*)pr = p01;
        *(u32*)(pr + 2) = p23;
      }
    }
    bf16x8 vf[4], pf[4];
#pragma unroll
    for (int dt = 0; dt < 4; ++dt) {
      int d = dt * 16 + (l & 15);
      int phys = (ks * 4 + (l >> 4)) ^ (d & 7);
      vf[dt] = *(const bf16x8*)&Vt[d * 512 + phys * 8];
    }
#pragma unroll
    for (int qt = 0; qt < 4; ++qt)
      pf[qt] = *(const bf16x8*)(Pw + (qt * 16 + (l & 15)) * 40 + (l >> 4) * 8);
#pragma unroll
    for (int dt = 0; dt < 4; ++dt)
#pragma unroll
      for (int qt = 0; qt < 4; ++qt)
        oacc[dt][qt] = __builtin_amdgcn_mfma_f32_16x16x32_bf16(vf[dt], pf[qt], oacc[dt][qt], 0, 0, 0);
  }

  float lmax = 0.f;
  u16* Ob = O + (long)(b * 512 + qbase) * C_ + h * 64;
#pragma unroll
  for (int qt = 0; qt < 4; ++qt) {
    float inv = 1.0f / lrun[qt];
    long qoff = (long)(qt * 16 + (l & 15)) * C_;
#pragma unroll
    for (int dt = 0; dt < 4; ++dt) {
      int d = dt * 16 + (l >> 4) * 4;
      float v0 = oacc[dt][qt][0] * inv;
      float v1 = oacc[dt][qt][1] * inv;
      float v2 = oacc[dt][qt][2] * inv;
      float v3 = oacc[dt][qt][3] * inv;
      lmax = fmaxf(fmaxf(lmax, fmaxf(fabsf(v0), fabsf(v1))), fmaxf(fabsf(v2), fabsf(v3)));
      u32 a01 = (u32)f2bf(v0) | ((u32)f2bf(v1) << 16);
      u32 a23 = (u32)f2bf(v2) | ((u32)f2bf(v3) << 16);
      *(u32*)(Ob + qoff + d) = a01;
      *(u32*)(Ob + qoff + d + 2) = a23;
    }
  }
  lmax = wredMax(lmax);
  if (l == 0) redm[w] = lmax;
  __syncthreads();
  if (tid == 0)
    slotAtomicMax(amax, blockIdx.x * 2 + blockIdx.y,
                  fmaxf(fmaxf(redm[0], redm[1]), fmaxf(redm[2], redm[3])));
}

// ---------------- int8 MFMA GEMM, BK=128 2-phase ----------------
// EPI: 0 = +bias -> bf16
//      1 = +bias + f32 resid -> bf16 (proj: h)
//      2 = +bias, gelu, absmax -> bf16
//      3 = +bias + bf16 resid -> f32 (final output)
template <int BM, int BN, int EPI, bool SWZ>
__global__ __launch_bounds__(256) void k_gemmq(
    const signed char* __restrict__ A, int lda,
    const signed char* __restrict__ Bm, int ldb,
    const float* __restrict__ bias,
    void* __restrict__ Cp, int ldc,
    int M, int N, int K,
    const void* __restrict__ resid,
    u32* __restrict__ amaxOut,
    const u32* __restrict__ amaxA, const u32* __restrict__ amaxB) {
  constexpr int BK = 128;
  constexpr int MF = (BM / 2) / 16;
  constexpr int NF = (BN / 2) / 16;
  constexpr int NLD = BM / 32 + BN / 32;
  __shared__ __align__(16) signed char As[2][BM * BK];
  __shared__ __align__(16) signed char Bs[2][BN * BK];
  const int tid = threadIdx.x;
  const int wid = tid >> 6, lane = tid & 63;
  const int wr = wid >> 1, wc = wid & 1;

  float sa = fmaxf(slotMax(amaxA) * (1.0f / 127.0f), 1e-8f);
  float sb = fmaxf(slotMax(amaxB) * (1.0f / 127.0f), 1e-8f);
  const float sAB = sa * sb;

  int bx = blockIdx.x, by = blockIdx.y;
  if (SWZ) {
    int gx = gridDim.x;
    int nwg = gx * gridDim.y;
    int bid = by * gx + bx;
    int cpx = nwg >> 3;
    int swz = (bid & 7) * cpx + (bid >> 3);
    bx = swz % gx;
    by = swz / gx;
  }

  const signed char* Ab = A + (long)by * BM * lda;
  const signed char* Bb = Bm + (long)bx * BN * ldb;

  i32x4 acc[MF][NF];
#pragma unroll
  for (int m = 0; m < MF; m++)
#pragma unroll
    for (int n = 0; n < NF; n++) acc[m][n] = (i32x4){0, 0, 0, 0};

  const int lr = lane & 15;
  const int l8 = lane >> 3;
  const int s8 = (lane & 7) ^ l8;
  const long aoff = (long)l8 * lda + s8 * 16;
  const long boff = (long)l8 * ldb + s8 * 16;

  auto stageAB = [&](int buf, int k0) {
#pragma unroll
    for (int i = 0; i < BM / 32; ++i) {
      int R0 = wid * (BM / 4) + i * 8;
      gload16(Ab + (long)R0 * lda + k0 + aoff, &As[buf][R0 * BK]);
    }
#pragma unroll
    for (int i = 0; i < BN / 32; ++i) {
      int R0 = wid * (BN / 4) + i * 8;
      gload16(Bb + (long)R0 * ldb + k0 + boff, &Bs[buf][R0 * BK]);
    }
  };

  auto waitCounted = [&]() {
    if constexpr (NLD == 8) {
      asm volatile("s_waitcnt vmcnt(8)" ::: "memory");
    } else if constexpr (NLD == 6) {
      asm volatile("s_waitcnt vmcnt(6)" ::: "memory");
    } else {
      asm volatile("s_waitcnt vmcnt(4)" ::: "memory");
    }
  };

  auto computeK = [&](int buf) {
#pragma unroll
    for (int kk = 0; kk < 2; ++kk) {
      const int sl = (kk << 2) + (lane >> 4);
      const int sf = (sl ^ (lr & 7)) << 4;
      i32x4 af[MF], bfr[NF];
#pragma unroll
      for (int m = 0; m < MF; m++)
        af[m] = *(const i32x4*)&As[buf][(wr * (BM / 2) + m * 16 + lr) * BK + sf];
#pragma unroll
      for (int n = 0; n < NF; n++)
        bfr[n] = *(const i32x4*)&Bs[buf][(wc * (BN / 2) + n * 16 + lr) * BK + sf];
      __builtin_amdgcn_s_setprio(1);
#pragma unroll
      for (int m = 0; m < MF; m++)
#pragma unroll
        for (int n = 0; n < NF; n++)
          acc[m][n] = __builtin_amdgcn_mfma_i32_16x16x64_i8(af[m], bfr[n], acc[m][n], 0, 0, 0);
      __builtin_amdgcn_s_setprio(0);
    }
  };

  const int nt = K / BK;
  stageAB(0, 0);
  int cur = 0;
  for (int t = 0; t < nt; ++t) {
    if (t + 1 < nt) {
      stageAB(cur ^ 1, (t + 1) * BK);
      waitCounted();
    } else {
      asm volatile("s_waitcnt vmcnt(0)" ::: "memory");
    }
    __builtin_amdgcn_s_barrier();
    computeK(cur);
    if (t + 1 < nt)
      __builtin_amdgcn_s_barrier();
    cur ^= 1;
  }

  const int rowBase = by * BM + wr * (BM / 2);
  const int colBase = bx * BN + wc * (BN / 2);
  float lmax = 0.f;
#pragma unroll
  for (int m = 0; m < MF; m++) {
    int row0 = rowBase + m * 16 + (lane >> 4) * 4;
#pragma unroll
    for (int n = 0; n < NF; n++) {
      int col = colBase + n * 16 + lr;
      float bs = bias[col];
#pragma unroll
      for (int j = 0; j < 4; j++) {
        int row = row0 + j;
        long idx = (long)row * ldc + col;
        float v = (float)acc[m][n][j] * sAB;
        if (EPI == 0) {
          ((u16*)Cp)[idx] = f2bf(v + bs);
        } else if (EPI == 1) {
          ((u16*)Cp)[idx] = f2bf(v + bs + ((const float*)resid)[idx]);
        } else if (EPI == 2) {
          v = gelu1(v + bs);
          lmax = fmaxf(fmaxf(lmax, v), 0.0f - v);
          ((u16*)Cp)[idx] = f2bf(v);
        } else if (EPI == 3) {
          ((float*)Cp)[idx] = v + bs + bf2f(((const u16*)resid)[idx]);
        }
      }
    }
  }
  if (EPI == 2) {
    __shared__ float redm[4];
    float wm = wredMax(lmax);
    if (lane == 0) redm[wid] = wm;
    __syncthreads();
    if (tid == 0) {
      float bm = fmaxf(fmaxf(redm[0], redm[1]), fmaxf(redm[2], redm[3]));
      slotAtomicMax(amaxOut, blockIdx.y * gridDim.x + blockIdx.x, bm);
    }
  }
}

// ---------------- 256x256 8-phase int8 GEMM (w1), counted vmcnt ----------------
__global__ __launch_bounds__(512, 1) void k_gemmq8(
    const signed char* __restrict__ A, int lda,
    const signed char* __restrict__ Bm, int ldb,
    const float* __restrict__ bias,
    u16* __restrict__ Cp, int ldc,
    int K,
    u32* __restrict__ amaxOut,
    const u32* __restrict__ amaxA, const u32* __restrict__ amaxB) {
  __shared__ __align__(16) signed char As[2][256 * 128];
  __shared__ __align__(16) signed char Bs[2][256 * 128];
  const int tid = threadIdx.x;
  const int wid = tid >> 6, lane = tid & 63;
  const int wr = wid >> 2, wc = wid & 3;
  const int lr = lane & 15;

  float sa = fmaxf(slotMax(amaxA) * (1.0f / 127.0f), 1e-8f);
  float sb = fmaxf(slotMax(amaxB) * (1.0f / 127.0f), 1e-8f);
  const float sAB = sa * sb;

  int bx = blockIdx.x, by = blockIdx.y;
  {
    int bid = by * 16 + bx;
    int swz = (bid & 7) * 32 + (bid >> 3);
    bx = swz & 15;
    by = swz >> 4;
  }
  const signed char* Ab = A + (long)by * 256 * lda;
  const signed char* Bb = Bm + (long)bx * 256 * ldb;

  i32x4 acc[8][4];
#pragma unroll
  for (int m = 0; m < 8; m++)
#pragma unroll
    for (int n = 0; n < 4; n++) acc[m][n] = (i32x4){0, 0, 0, 0};

  const int l8 = lane >> 3;
  const int s8 = (lane & 7) ^ l8;
  const long aoff = (long)l8 * lda + s8 * 16;
  const long boff = (long)l8 * ldb + s8 * 16;

  auto stageHalf = [&](int buf, int kt, int h) {
    int k0 = kt * 128;
    if (h < 2) {
      int R0 = h * 128 + wid * 16;
      gload16(Ab + (long)R0 * lda + k0 + aoff, &As[buf][R0 * 128]);
      gload16(Ab + (long)(R0 + 8) * lda + k0 + aoff, &As[buf][(R0 + 8) * 128]);
    } else {
      int R0 = (h - 2) * 128 + wid * 16;
      gload16(Bb + (long)R0 * ldb + k0 + boff, &Bs[buf][R0 * 128]);
      gload16(Bb + (long)(R0 + 8) * ldb + k0 + boff, &Bs[buf][(R0 + 8) * 128]);
    }
  };

  const int nt = K / 128;
#define PHASE(BUF, MH, KS, STAGESTMT)                                              \
  {                                                                                \
    const int slotl = (KS) * 4 + (lane >> 4);                                      \
    i32x4 af[4], bfr[4];                                                           \
    _Pragma("unroll") for (int i = 0; i < 4; ++i) {                                \
      int row = wr * 128 + ((MH) * 4 + i) * 16 + lr;                               \
      af[i] = *(const i32x4*)&As[BUF][row * 128 + ((slotl ^ (row & 7)) << 4)];     \
    }                                                                              \
    _Pragma("unroll") for (int n = 0; n < 4; ++n) {                                \
      int row = wc * 64 + n * 16 + lr;                                             \
      bfr[n] = *(const i32x4*)&Bs[BUF][row * 128 + ((slotl ^ (row & 7)) << 4)];    \
    }                                                                              \
    STAGESTMT;                                                                     \
    __builtin_amdgcn_s_barrier();                                                  \
    __builtin_amdgcn_s_setprio(1);                                                 \
    _Pragma("unroll") for (int i = 0; i < 4; ++i)                                  \
      _Pragma("unroll") for (int n = 0; n < 4; ++n)                                \
        acc[(MH) * 4 + i][n] =                                                     \
            __builtin_amdgcn_mfma_i32_16x16x64_i8(af[i], bfr[n], acc[(MH) * 4 + i][n], 0, 0, 0); \
    __builtin_amdgcn_s_setprio(0);                                                 \
    __builtin_amdgcn_s_barrier();                                                  \
  }

  stageHalf(0, 0, 0);
  stageHalf(0, 0, 2);
  stageHalf(0, 0, 3);
  stageHalf(0, 0, 1);

  int cur = 0;
  for (int t = 0; t < nt; ++t) {
    const bool stg = (t + 1 < nt);
    const int nb = cur ^ 1;
    const int tn = t + 1;
    asm volatile("s_waitcnt vmcnt(2)" ::: "memory");
    __builtin_amdgcn_s_barrier();
    PHASE(cur, 0, 0, { if (stg) stageHalf(nb, tn, 0); })
    PHASE(cur, 0, 1, { if (stg) stageHalf(nb, tn, 2); })
    if (stg) {
      asm volatile("s_waitcnt vmcnt(4)" ::: "memory");
    } else {
      asm volatile("s_waitcnt vmcnt(0)" ::: "memory");
    }
    __builtin_amdgcn_s_barrier();
    PHASE(cur, 1, 0, { if (stg) stageHalf(nb, tn, 3); })
    PHASE(cur, 1, 1, { if (stg) stageHalf(nb, tn, 1); })
    cur = nb;
  }
#undef PHASE

  const int rowBase = by * 256 + wr * 128;
  const int colBase = bx * 256 + wc * 64;
  float lmax = 0.f;
#pragma unroll
  for (int m = 0; m < 8; m++) {
    int row0 = rowBase + m * 16 + (lane >> 4) * 4;
#pragma unroll
    for (int n = 0; n < 4; n++) {
      int col = colBase + n * 16 + lr;
      float bs = bias[col];
#pragma unroll
      for (int j = 0; j < 4; j++) {
        long idx = (long)(row0 + j) * ldc + col;
        float v = gelu1((float)acc[m][n][j] * sAB + bs);
        lmax = fmaxf(fmaxf(lmax, v), 0.0f - v);
        Cp[idx] = f2bf(v);
      }
    }
  }
  {
    __shared__ float redm[8];
    float wm = wredMax(lmax);
    if (lane == 0) redm[wid] = wm;
    __syncthreads();
    if (tid == 0) {
      float bm = redm[0];
#pragma unroll
      for (int i = 1; i < 8; ++i) bm = fmaxf(bm, redm[i]);
      slotAtomicMax(amaxOut, blockIdx.y * gridDim.x + blockIdx.x, bm);
    }
  }
}

// ---------------- host ----------------
extern "C" void kernel_launch(void* const* d_in, const int* in_sizes, int n_in,
                              void* d_out, int out_size, void* d_ws, size_t ws_size,
                              hipStream_t stream) {
  const float* hidden = (const float*)d_in[0];
  const float* mask = (const float*)d_in[1];
  const float* ln1g = (const float*)d_in[2];
  const float* ln1b = (const float*)d_in[3];
  const float* ln2g = (const float*)d_in[4];
  const float* ln2b = (const float*)d_in[5];
  const float* w_qkv = (const float*)d_in[6];
  const float* b_qkv = (const float*)d_in[7];
  const float* w_out = (const float*)d_in[8];
  const float* b_out = (const float*)d_in[9];
  const float* w1 = (const float*)d_in[10];
  const float* b1 = (const float*)d_in[11];
  const float* w2 = (const float*)d_in[12];
  const float* b2 = (const float*)d_in[13];

  char* ws = (char*)d_ws;
  u32* sc = (u32*)ws;
  const long MB = 1024 * 1024;
  signed char* wq_qkv = (signed char*)(ws + 1 * MB);
  signed char* wq_out = (signed char*)(ws + 4 * MB);
  signed char* wq_w1  = (signed char*)(ws + 6 * MB);
  signed char* wq_w2  = (signed char*)(ws + 10 * MB);
  signed char* xq     = (signed char*)(ws + 14 * MB);
  u16* x1             = (u16*)(ws + 18 * MB);
  signed char* Oq     = (signed char*)(ws + 26 * MB);
  u16* O              = (u16*)(ws + 30 * MB);
  u16* qkv            = (u16*)(ws + 38 * MB);
  u16* hbuf           = (u16*)(ws + 62 * MB);   // h in bf16 (8 MB)
  u16* y1             = (u16*)(ws + 78 * MB);
  signed char* y1q    = (signed char*)(ws + 110 * MB);

  k_init<<<32, 256, 0, stream>>>(sc);

  // fused: weight absmax (blocks 0-511) + LN1 (blocks 512-4607)
  k_pre1<<<512 + BT, 256, 0, stream>>>(
      w_qkv, 3 * C_ * C_ / 4, w_out, C_ * C_ / 4, w1, I_ * C_ / 4, w2, C_ * I_ / 4, sc,
      hidden, ln1g, ln1b, x1, sc + 4 * 1024);

  // fused: weight quant (blocks 0-511) + x1 quant (blocks 512-1023)
  k_pre2<<<1024, 256, 0, stream>>>(
      w_qkv, wq_qkv, 3 * C_ * C_ / 4, w_out, wq_out, C_ * C_ / 4,
      w1, wq_w1, I_ * C_ / 4, w2, wq_w2, C_ * I_ / 4, sc,
      x1, xq, BT * C_ / 8, sc + 4 * 1024);

  // qkv = (xq . wq_qkv^T)*s + b -> bf16 [4096,3072]
  k_gemmq<128, 128, 0, true><<<dim3(24, 32), 256, 0, stream>>>(
      xq, C_, wq_qkv, C_, b_qkv, qkv, 3 * C_,
      BT, 3 * C_, C_, nullptr, nullptr, sc + 4 * 1024, sc + 0 * 1024);

  // fused attention -> O bf16 [4096,1024], + amax
  k_attn<<<dim3(NH, 2), 256, 0, stream>>>(qkv, mask, O, sc + 5 * 1024);
  k_quant_b8<<<512, 256, 0, stream>>>(O, Oq, BT * C_ / 8, sc + 5 * 1024);

  // h = hidden + (Oq . wq_out^T)*s + b -> bf16 hbuf
  k_gemmq<64, 64, 1, true><<<dim3(16, 64), 256, 0, stream>>>(
      Oq, C_, wq_out, C_, b_out, hbuf, C_,
      BT, C_, C_, hidden, nullptr, sc + 5 * 1024, sc + 1 * 1024);

  // LN2 (bf16 in/out) + quant
  k_lnb<<<BT, 256, 0, stream>>>(hbuf, ln2g, ln2b, x1, sc + 6 * 1024);
  k_quant_b8<<<512, 256, 0, stream>>>(x1, xq, BT * C_ / 8, sc + 6 * 1024);

  // y1 = gelu((xq . wq_w1^T)*s + b1) -> bf16 [4096,4096], + amax  (8-phase 256^2)
  k_gemmq8<<<dim3(16, 16), 512, 0, stream>>>(
      xq, C_, wq_w1, C_, b1, y1, I_, C_,
      sc + 7 * 1024, sc + 6 * 1024, sc + 2 * 1024);
  k_quant_b8<<<512, 256, 0, stream>>>(y1, y1q, BT * I_ / 8, sc + 7 * 1024);

  // out = (y1q . wq_w2^T)*s + b2 + h(bf16) -> f32 d_out
  k_gemmq<64, 64, 3, true><<<dim3(16, 64), 256, 0, stream>>>(
      y1q, I_, wq_w2, I_, b2, d_out, C_,
      BT, C_, I_, hbuf, nullptr, sc + 7 * 1024, sc + 3 * 1024);
}